// Round 15
// baseline (168.828 us; speedup 1.0000x reference)
//
#include <hip/hip_runtime.h>

#define B_ 64
#define N_ 64
#define D_ 256
#define LAP_ 16
#define M_ 2016           // 64*63/2
#define TOK_ 2081         // 1 + 64 + 2016

typedef float v4f __attribute__((ext_vector_type(4)));

// Map linear upper-tri index m -> (i, j), i<j, row-major over triu(k=1).
__device__ __forceinline__ void ij_from_m(int m, int& i, int& j) {
    float fm = (float)m;
    int gi = (int)((127.0f - sqrtf(127.0f * 127.0f - 8.0f * fm)) * 0.5f);
    if (gi < 0) gi = 0;
    if (gi > 62) gi = 62;
    while (gi > 0 && (127 * gi - gi * gi) / 2 > m) gi--;
    while (gi < 62 && (127 * (gi + 1) - (gi + 1) * (gi + 1)) / 2 <= m) gi++;
    i = gi;
    j = gi + 1 + (m - (127 * gi - gi * gi) / 2);
}

// ---------------------------------------------------------------------------
// Kernel A: 16-way role-split prep. Grid (B, 16) = 1024 blocks, 256 threads.
// R15 hybrid: role 0 keeps the MASK scatter (R12 placement — free in this
// latency-bound block; R14 proved it regresses inside edge's store stream)
// but drops the SRC scatter (edge recomputes rank inline — R14 mechanism).
//   role 0    : compaction (adj->LDS, ballot, scan -> ws words/pref/total;
//               edge-mask scatter)
//   roles 1-4 : U = eig.W1, 16 nodes each
//   roles 5-8 : V = eig.W2, 16 nodes each
//   roles 9-15: node tokens, 9-10 nodes each; role 9 + graph tok + mask head
// bid%8 == b%8 for every role -> batch pinned to XCD b%8 (matches edge).
// ---------------------------------------------------------------------------
__global__ __launch_bounds__(256, 2) void prep_kernel(
    const int*   __restrict__ adj,
    const float* __restrict__ node_feats,
    const float* __restrict__ eigvec,
    const float* __restrict__ W_lap,
    const float* __restrict__ W_edge,
    const float* __restrict__ graph_tok,
    float*       __restrict__ out,
    unsigned long long* __restrict__ wwords,
    int*         __restrict__ wpref,
    int*         __restrict__ wtotal,
    float*       __restrict__ Uall,
    float*       __restrict__ Vall)
{
    const int b    = blockIdx.x;
    const int role = blockIdx.y;               // 0..15
    const int t    = threadIdx.x;
    const int wave = t >> 6, lane = t & 63;

    if (role == 0) {
        // ---- compaction + mask scatter ----
        __shared__ int sAdj[N_ * N_];              // 16 KB
        __shared__ unsigned long long sWords[32];
        __shared__ int sPref[32];
        __shared__ int sTotal;
#pragma unroll
        for (int r = 0; r < 4; r++)
            ((int4*)sAdj)[r * 256 + t] =
                ((const int4*)(adj + (size_t)b * (N_ * N_)))[r * 256 + t];
        __syncthreads();
#pragma unroll
        for (int k = 0; k < 8; k++) {
            int m = k * 256 + t;
            int valid = 0;
            if (m < M_) {
                int i, j;
                ij_from_m(m, i, j);
                valid = (sAdj[i * N_ + j] > 0) ? 1 : 0;
            }
            unsigned long long blt = __ballot(valid);
            if (lane == 0) sWords[k * 4 + wave] = blt;
        }
        __syncthreads();
        if (t < 32) {
            unsigned long long word = sWords[t];
            int cnt = __popcll(word);
            int inc = cnt;
#pragma unroll
            for (int off = 1; off < 32; off <<= 1) {
                int v = __shfl_up(inc, off);
                if (lane >= off) inc += v;
            }
            wwords[b * 32 + t] = word;
            wpref [b * 32 + t] = inc - cnt;
            sPref[t] = inc - cnt;
            if (t == 31) { wtotal[b] = inc; sTotal = inc; }
        }
        __syncthreads();
        const int total = sTotal;
        float* maskb = out + (size_t)B_ * TOK_ * D_ + (size_t)b * TOK_;
#pragma unroll
        for (int k = 0; k < 8; k++) {
            int m = k * 256 + t;
            if (m < M_) {
                int w = m >> 6, r = m & 63;
                unsigned long long word = sWords[w];
                int rank = sPref[w] + __popcll(word & ((1ull << r) - 1ull));
                int valid = (int)((word >> r) & 1ull);
                int p = valid ? rank : total + (m - rank);
                maskb[1 + N_ + p] = valid ? 0.0f : 1.0f;
            }
        }
        return;
    }

    // roles 1-15 use eigvec only
    __shared__ float sEig[N_ * LAP_];              // 4 KB
    ((float4*)sEig)[t] = ((const float4*)(eigvec + (size_t)b * N_ * LAP_))[t];

    if (role <= 8) {
        // ---- U (roles 1-4) or V (roles 5-8): 16 nodes, thread owns col t ----
        const int isV = (role >= 5);
        const int n0  = (isV ? (role - 5) : (role - 1)) * 16;
        const float* Wsel = isV ? (W_edge + (1 + LAP_) * D_) : (W_edge + D_);
        float wc[LAP_];
#pragma unroll
        for (int l = 0; l < LAP_; l++) wc[l] = Wsel[l * D_ + t];
        __syncthreads();

        float* Tb = (isV ? Vall : Uall) + (size_t)b * N_ * D_;
#pragma unroll 4
        for (int k = 0; k < 16; k++) {
            int n = n0 + k;
            const float* e = sEig + n * LAP_;      // wave-uniform broadcast
            float acc = 0.0f;
#pragma unroll
            for (int l = 0; l < LAP_; l++) acc += e[l] * wc[l];
            Tb[n * D_ + t] = acc;
        }
        return;
    }

    // ---- roles 9-15: node tokens (9-10 nodes each) ----
    float wlc[LAP_];
#pragma unroll
    for (int l = 0; l < LAP_; l++) wlc[l] = W_lap[l * D_ + t];
    __syncthreads();

    const int r9 = role - 9;                       // 0..6
    const int n0 = r9 * 9;                         // 0,9,..,54
    const int n1 = (r9 == 6) ? 64 : n0 + 9;
    float* outB = out + (size_t)b * TOK_ * D_;
    for (int n = n0; n < n1; n++) {
        float a = node_feats[((size_t)b * N_ + n) * D_ + t];
        const float* e = sEig + n * LAP_;
#pragma unroll
        for (int l = 0; l < LAP_; l++) a += e[l] * wlc[l];
        outB[(size_t)(1 + n) * D_ + t] = a;
    }
    if (role == 9) {
        outB[t] = graph_tok[t];                    // graph token
        float* maskb = out + (size_t)B_ * TOK_ * D_ + (size_t)b * TOK_;
        if (t < 1 + N_) maskb[t] = 0.0f;           // mask head
    }
}

// ---------------------------------------------------------------------------
// Kernel B: source-ordered edge-token streamer, inline rank, NO mask writes
// (they regressed here in R14 — moved back to prep). Grid 2048, 256 threads,
// zero LDS, (256,8) -> 32 waves/CU. Block: b = bid&63 (XCD-pinned),
// s = bid>>6 owns source edges [s*63, s*63+63). Per token: rank/p from
// lane-resident words/pref via __shfl, U/V gather (L2), 1 KB row store.
// ---------------------------------------------------------------------------
__global__ __launch_bounds__(256, 8) void edge_kernel(
    const float* __restrict__ Uall,
    const float* __restrict__ Vall,
    const unsigned long long* __restrict__ wwords,
    const int*   __restrict__ wpref,
    const int*   __restrict__ wtotal,
    const float* __restrict__ W_edge,
    const float* __restrict__ b_edge,
    const float* __restrict__ type_embed,
    float*       __restrict__ out)
{
    const int bid  = blockIdx.x;         // 0..2047
    const int b    = bid & 63;           // batch (bid%8 == b%8 -> XCD pin)
    const int s    = bid >> 6;           // 0..31: source chunk
    const int wave = threadIdx.x >> 6, lane = threadIdx.x & 63;

    v4f base4 = ((const v4f*)W_edge)[lane];
    base4 += ((const v4f*)b_edge)[lane];
    base4 += ((const v4f*)(type_embed + D_))[lane];

    const float* Ub = Uall + (size_t)b * N_ * D_;
    const float* Vb = Vall + (size_t)b * N_ * D_;
    unsigned long long myword = (lane < 32) ? wwords[b * 32 + lane] : 0ull;
    int mypref = (lane < 32) ? wpref[b * 32 + lane] : 0;
    const int total = wtotal[b];
    float* outE = out + (size_t)b * TOK_ * D_ + (size_t)(1 + N_) * D_;

    const int m0 = s * 63;               // this block: source edges [m0, m0+63)
#pragma unroll 4
    for (int q = wave; q < 63; q += 4) {
        int m = m0 + q;                  // wave-uniform
        int w = m >> 6, rr = m & 63;
        unsigned long long word = __shfl(myword, w);
        int pw = __shfl(mypref, w);
        int rank = pw + __popcll(word & ((1ull << rr) - 1ull));
        int valid = (int)((word >> rr) & 1ull);
        int p = valid ? rank : total + (m - rank);
        v4f val = {0.0f, 0.0f, 0.0f, 0.0f};
        if (valid) {                     // wave-uniform branch
            int i, j;
            ij_from_m(m, i, j);
            v4f u = ((const v4f*)(Ub + i * D_))[lane];
            v4f v = ((const v4f*)(Vb + j * D_))[lane];
            val = base4 + u + v;
        }
        ((v4f*)(outE + (size_t)p * D_))[lane] = val;
    }
}

extern "C" void kernel_launch(void* const* d_in, const int* in_sizes, int n_in,
                              void* d_out, int out_size, void* d_ws, size_t ws_size,
                              hipStream_t stream) {
    const int*   adj        = (const int*)d_in[0];
    const float* node_feats = (const float*)d_in[1];
    const float* eigvec     = (const float*)d_in[2];
    const float* W_lap      = (const float*)d_in[3];
    const float* W_edge     = (const float*)d_in[4];
    const float* b_edge     = (const float*)d_in[5];
    const float* type_embed = (const float*)d_in[6];
    const float* graph_tok  = (const float*)d_in[7];
    float* out = (float*)d_out;

    // ws layout:
    //   [0,16K)      words[B][32] u64
    //   [16K,24K)    pref[B][32]  int
    //   [24K,24.25K) total[B]     int
    //   [32K,...)    U[B][N][D] f32 | V[B][N][D] f32   (~8.03 MB total)
    unsigned long long* wwords = (unsigned long long*)d_ws;
    int*   wpref  = (int*)((char*)d_ws + 16 * 1024);
    int*   wtotal = (int*)((char*)d_ws + 24 * 1024);
    float* Uall   = (float*)((char*)d_ws + 32 * 1024);
    float* Vall   = Uall + (size_t)B_ * N_ * D_;

    prep_kernel<<<dim3(B_, 16), dim3(256), 0, stream>>>(
        adj, node_feats, eigvec, W_lap, W_edge, graph_tok,
        out, wwords, wpref, wtotal, Uall, Vall);
    edge_kernel<<<dim3(2048), dim3(256), 0, stream>>>(
        Uall, Vall, wwords, wpref, wtotal, W_edge, b_edge, type_embed, out);
}

// Round 16
// 163.955 us; speedup vs baseline: 1.0297x; 1.0297x over previous
//
#include <hip/hip_runtime.h>

#define B_ 64
#define N_ 64
#define D_ 256
#define LAP_ 16
#define M_ 2016           // 64*63/2
#define TOK_ 2081         // 1 + 64 + 2016

typedef float v4f __attribute__((ext_vector_type(4)));

// Map linear upper-tri index m -> (i, j), i<j, row-major over triu(k=1).
__device__ __forceinline__ void ij_from_m(int m, int& i, int& j) {
    float fm = (float)m;
    int gi = (int)((127.0f - sqrtf(127.0f * 127.0f - 8.0f * fm)) * 0.5f);
    if (gi < 0) gi = 0;
    if (gi > 62) gi = 62;
    while (gi > 0 && (127 * gi - gi * gi) / 2 > m) gi--;
    while (gi < 62 && (127 * (gi + 1) - (gi + 1) * (gi + 1)) / 2 <= m) gi++;
    i = gi;
    j = gi + 1 + (m - (127 * gi - gi * gi) / 2);
}

// ---------------------------------------------------------------------------
// R16 == R12 (verified best, 163.8 us). 16-way role-split prep +
// src-array edge streamer. R14/R15 proved inline rank costs ~5 us (store
// address generation lands on a ~40-cycle shfl/popcll chain); R12's
// prefetched src codes keep store addresses register-ready.
//
// Kernel A: Grid (B, 16) = 1024 blocks (4/CU, 16 waves/CU).
//   role 0    : compaction (adj->LDS, ballot, scan, src scatter, edge mask,
//               mask head)
//   roles 1-4 : U = eig.W1, 16 nodes each
//   roles 5-8 : V = eig.W2, 16 nodes each
//   roles 9-15: node tokens, 9-10 nodes each; role 9 + graph tok + base row
//   ws: base[256] | U[B][N][D] | V[B][N][D] | src[B][M] (ints)
// bid%8 == b%8 for every role -> batch pinned to XCD b%8 (matches edge).
// ---------------------------------------------------------------------------
__global__ __launch_bounds__(256, 2) void prep_kernel(
    const int*   __restrict__ adj,
    const float* __restrict__ node_feats,
    const float* __restrict__ eigvec,
    const float* __restrict__ W_lap,
    const float* __restrict__ W_edge,
    const float* __restrict__ b_edge,
    const float* __restrict__ type_embed,
    const float* __restrict__ graph_tok,
    float*       __restrict__ out,
    float*       __restrict__ wsf,
    int*         __restrict__ src)
{
    const int b    = blockIdx.x;
    const int role = blockIdx.y;               // 0..15
    const int t    = threadIdx.x;
    const int wave = t >> 6, lane = t & 63;

    if (role == 0) {
        // ---- compaction ----
        __shared__ int sAdj[N_ * N_];              // 16 KB
        __shared__ unsigned long long sWords[32];
        __shared__ int sPref[32];
        __shared__ int sTotal;

#pragma unroll
        for (int r = 0; r < 4; r++)
            ((int4*)sAdj)[r * 256 + t] =
                ((const int4*)(adj + (size_t)b * (N_ * N_)))[r * 256 + t];
        __syncthreads();

#pragma unroll
        for (int k = 0; k < 8; k++) {
            int m = k * 256 + t;
            int valid = 0;
            if (m < M_) {
                int i, j;
                ij_from_m(m, i, j);
                valid = (sAdj[i * N_ + j] > 0) ? 1 : 0;
            }
            unsigned long long blt = __ballot(valid);
            if (lane == 0) sWords[k * 4 + wave] = blt;
        }
        __syncthreads();

        if (t < 32) {
            int cnt = __popcll(sWords[t]);
            int inc = cnt;
#pragma unroll
            for (int off = 1; off < 32; off <<= 1) {
                int v = __shfl_up(inc, off);
                if (lane >= off) inc += v;
            }
            sPref[t] = inc - cnt;
            if (t == 31) sTotal = inc;
        }
        __syncthreads();

        const int total = sTotal;
        float* maskb = out + (size_t)B_ * TOK_ * D_ + (size_t)b * TOK_;
#pragma unroll
        for (int k = 0; k < 8; k++) {
            int m = k * 256 + t;
            if (m < M_) {
                int w = m >> 6, r = m & 63;
                unsigned long long word = sWords[w];
                int rank = sPref[w] + __popcll(word & ((1ull << r) - 1ull));
                int valid = (int)((word >> r) & 1ull);
                int p = valid ? rank : total + (m - rank);
                int i, j;
                ij_from_m(m, i, j);
                src[b * M_ + p] = i | (j << 6) | (valid << 12);
                maskb[1 + N_ + p] = valid ? 0.0f : 1.0f;
            }
        }
        if (t < 1 + N_) maskb[t] = 0.0f;           // mask head
        return;
    }

    // roles 1-15 use eigvec only
    __shared__ float sEig[N_ * LAP_];              // 4 KB
    ((float4*)sEig)[t] = ((const float4*)(eigvec + (size_t)b * N_ * LAP_))[t];

    if (role <= 8) {
        // ---- U (roles 1-4) or V (roles 5-8): 16 nodes, thread owns col t ----
        const int isV = (role >= 5);
        const int n0  = (isV ? (role - 5) : (role - 1)) * 16;
        const float* Wsel = isV ? (W_edge + (1 + LAP_) * D_) : (W_edge + D_);
        float wc[LAP_];
#pragma unroll
        for (int l = 0; l < LAP_; l++) wc[l] = Wsel[l * D_ + t];
        __syncthreads();

        float* Tb = wsf + 256 + (size_t)b * N_ * D_
                  + (isV ? (size_t)B_ * N_ * D_ : 0);
#pragma unroll 4
        for (int k = 0; k < 16; k++) {
            int n = n0 + k;
            const float* e = sEig + n * LAP_;      // wave-uniform broadcast
            float acc = 0.0f;
#pragma unroll
            for (int l = 0; l < LAP_; l++) acc += e[l] * wc[l];
            Tb[n * D_ + t] = acc;
        }
        return;
    }

    // ---- roles 9-15: node tokens (9-10 nodes each) ----
    float wlc[LAP_];
#pragma unroll
    for (int l = 0; l < LAP_; l++) wlc[l] = W_lap[l * D_ + t];
    __syncthreads();

    const int r9 = role - 9;                       // 0..6
    const int n0 = r9 * 9;                         // 0,9,..,54
    const int n1 = (r9 == 6) ? 64 : n0 + 9;
    float* outB = out + (size_t)b * TOK_ * D_;
    for (int n = n0; n < n1; n++) {
        float a = node_feats[((size_t)b * N_ + n) * D_ + t];
        const float* e = sEig + n * LAP_;
#pragma unroll
        for (int l = 0; l < LAP_; l++) a += e[l] * wlc[l];
        outB[(size_t)(1 + n) * D_ + t] = a;
    }
    if (role == 9) {
        outB[t] = graph_tok[t];                    // graph token
        if (b == 0)
            wsf[t] = W_edge[t] + b_edge[t] + type_embed[D_ + t];  // base row
    }
}

// ---------------------------------------------------------------------------
// Kernel B: destination-ordered edge-token streamer (R9/R11/R12 form).
// Grid 2048, 256 threads, zero LDS, (256,8) -> 32 waves/CU. Each wave
// prefetches its 16 src codes with ONE vector load (lanes 0..15) and
// broadcasts per iteration via __shfl -> store addresses register-ready.
// ---------------------------------------------------------------------------
__global__ __launch_bounds__(256, 8) void edge_kernel(
    const float* __restrict__ wsf,
    const int*   __restrict__ src,
    float*       __restrict__ out)
{
    const int bid  = blockIdx.x;         // 0..2047
    const int xcd  = bid & 7;
    const int idx  = bid >> 3;           // 0..255
    const int b    = ((idx & 7) << 3) | xcd;   // batch, pinned to XCD b&7
    const int s    = idx >> 3;           // 0..31: dest chunk within batch
    const int wave = threadIdx.x >> 6, lane = threadIdx.x & 63;

    v4f base4 = ((const v4f*)wsf)[lane];
    const float* Ub = wsf + 256 + (size_t)b * N_ * D_;
    const float* Vb = Ub + (size_t)B_ * N_ * D_;
    const int* sb = src + b * M_;
    float* outE = out + (size_t)b * TOK_ * D_ + (size_t)(1 + N_) * D_;

    const int p0 = s * 63;               // this block: dest rows [p0, p0+63)
    // wave handles p = p0 + wave + 4q; prefetch all its infos in one load
    const int q15 = lane & 15;
    const int nq  = (63 - wave + 3) >> 2;          // 16,16,16,15
    int myinfo = (wave + 4 * q15 < 63) ? sb[p0 + wave + 4 * q15] : 0;

#pragma unroll 4
    for (int q = 0; q < nq; q++) {
        int info = __shfl(myinfo, q);    // VALU broadcast, no memory chain
        int p = p0 + wave + 4 * q;
        v4f val = {0.0f, 0.0f, 0.0f, 0.0f};
        if (info & (1 << 12)) {          // wave-uniform branch
            int si = info & 63, di = (info >> 6) & 63;
            v4f u = ((const v4f*)(Ub + si * D_))[lane];
            v4f v = ((const v4f*)(Vb + di * D_))[lane];
            val = base4 + u + v;
        }
        ((v4f*)(outE + (size_t)p * D_))[lane] = val;
    }
}

extern "C" void kernel_launch(void* const* d_in, const int* in_sizes, int n_in,
                              void* d_out, int out_size, void* d_ws, size_t ws_size,
                              hipStream_t stream) {
    const int*   adj        = (const int*)d_in[0];
    const float* node_feats = (const float*)d_in[1];
    const float* eigvec     = (const float*)d_in[2];
    const float* W_lap      = (const float*)d_in[3];
    const float* W_edge     = (const float*)d_in[4];
    const float* b_edge     = (const float*)d_in[5];
    const float* type_embed = (const float*)d_in[6];
    const float* graph_tok  = (const float*)d_in[7];
    float* out = (float*)d_out;

    // ws layout: base[256] | U[B][N][D] | V[B][N][D] | src[B][M] ints  (~8.8 MB)
    float* wsf = (float*)d_ws;
    int*   src = (int*)(wsf + 256 + 2 * (size_t)B_ * N_ * D_);

    prep_kernel<<<dim3(B_, 16), dim3(256), 0, stream>>>(
        adj, node_feats, eigvec, W_lap, W_edge, b_edge, type_embed, graph_tok,
        out, wsf, src);
    edge_kernel<<<dim3(2048), dim3(256), 0, stream>>>(wsf, src, out);
}